// Round 1
// baseline (650.940 us; speedup 1.0000x reference)
//
#include <hip/hip_runtime.h>

// ---------------------------------------------------------------------------
// VeRA Linear: y = x @ (W + 4*diag(b) B diag(d) A)^T + bias
// T=8192, IN=OUT=4096, R=256, all fp32 in/out. Strategy: fold delta into W
// in bf16 (small MFMA GEMM), then one 8192x4096x4096 bf16 MFMA GEMM (m97
// structure: 128x128 tile, global_load_lds width 16, 16x16x32 bf16 MFMA).
// ---------------------------------------------------------------------------

typedef __attribute__((ext_vector_type(8))) short short8;   // 8 bf16 = 4 VGPRs
typedef __attribute__((ext_vector_type(4))) float f32x4;    // MFMA acc

__device__ __forceinline__ unsigned short f2bf(float f) {
  union { float f; unsigned int u; } c; c.f = f;
  unsigned int u = c.u;
  unsigned int r = (u + 0x7fffu + ((u >> 16) & 1u)) >> 16;  // RNE, finite inputs
  return (unsigned short)r;
}

__device__ __forceinline__ void gl2lds16(const unsigned short* g, unsigned short* l) {
  __builtin_amdgcn_global_load_lds(
      (const __attribute__((address_space(1))) unsigned int*)g,
      (__attribute__((address_space(3))) unsigned int*)l, 16, 0, 0);
}

// fp32 -> bf16 bulk convert (x), float4 loads / 8B stores
__global__ __launch_bounds__(256) void k_cvt(const float* __restrict__ s,
                                             unsigned short* __restrict__ d, int n4) {
  int i = blockIdx.x * 256 + threadIdx.x;
  if (i >= n4) return;
  const float4 v = ((const float4*)s)[i];
  union { unsigned short u[4]; unsigned long long ll; } o;
  o.u[0] = f2bf(v.x); o.u[1] = f2bf(v.y); o.u[2] = f2bf(v.z); o.u[3] = f2bf(v.w);
  ((unsigned long long*)d)[i] = o.ll;
}

// Bd[o][r] = bf16(4 * b[o] * B[o][r] * d[r]);  AbT[i][r] = bf16(A[r][i])
// (OUT == IN == 4096 so one index space serves both)
__global__ __launch_bounds__(256) void k_prep(const float* __restrict__ Bv,
                                              const float* __restrict__ Av,
                                              const float* __restrict__ dv,
                                              const float* __restrict__ bv,
                                              unsigned short* __restrict__ Bd,
                                              unsigned short* __restrict__ AbT) {
  int idx = blockIdx.x * 256 + threadIdx.x;   // 4096*256 threads
  int o = idx >> 8, r = idx & 255;
  Bd[idx]  = f2bf(4.0f * bv[o] * Bv[idx] * dv[r]);
  AbT[idx] = f2bf(Av[(size_t)r * 4096 + o]);  // strided read; A is 4MB, L2/L3-resident
}

// C[m][n] = sum_k Amat[m][k]*Bmat[n][k]  (both row-major, K contiguous)
// FOLD=1: outB[m*N+n] = bf16(extra[m*N+n] + acc)   (extra = base W)
// FOLD=0: outF[m*N+n] = acc + extra[n]             (extra = bias)
template <int FOLD>
__global__ __launch_bounds__(256) void gemm_bt(const unsigned short* __restrict__ Amat,
                                               const unsigned short* __restrict__ Bmat,
                                               int K, int N,
                                               const float* __restrict__ extra,
                                               float* __restrict__ outF,
                                               unsigned short* __restrict__ outB) {
  __shared__ unsigned short As[128 * 32];   // 8KB, unpadded (global_load_lds constraint)
  __shared__ unsigned short Bs[128 * 32];   // 8KB

  const int tid  = threadIdx.x;
  const int lane = tid & 63;
  const int wave = tid >> 6;     // 4 waves
  const int wm   = wave >> 1;    // 2x2 wave grid of 64x64 quadrants
  const int wn   = wave & 1;
  const int quad = lane >> 4;    // 0..3
  const int m16  = lane & 15;

  const int blockN = blockIdx.x * 128;
  const int blockM = blockIdx.y * 128;

  // staging: each wave fills 2 x 16-row segments of each 128x32 tile
  const int ldRow = lane >> 2;        // 0..15
  const int ldCol = (lane & 3) * 8;   // 0,8,16,24
  const int seg0  = wave * 2;

  const size_t aOff0 = (size_t)(blockM + seg0 * 16 + ldRow) * K + ldCol;
  const size_t aOff1 = (size_t)(blockM + seg0 * 16 + 16 + ldRow) * K + ldCol;
  const size_t bOff0 = (size_t)(blockN + seg0 * 16 + ldRow) * K + ldCol;
  const size_t bOff1 = (size_t)(blockN + seg0 * 16 + 16 + ldRow) * K + ldCol;

  unsigned short* lA0 = &As[(seg0 * 16 + ldRow) * 32 + ldCol];
  unsigned short* lA1 = &As[(seg0 * 16 + 16 + ldRow) * 32 + ldCol];
  unsigned short* lB0 = &Bs[(seg0 * 16 + ldRow) * 32 + ldCol];
  unsigned short* lB1 = &Bs[(seg0 * 16 + 16 + ldRow) * 32 + ldCol];

  f32x4 acc[4][4];
#pragma unroll
  for (int i = 0; i < 4; ++i)
#pragma unroll
    for (int j = 0; j < 4; ++j) acc[i][j] = (f32x4){0.f, 0.f, 0.f, 0.f};

  const short8* Asv = (const short8*)As;
  const short8* Bsv = (const short8*)Bs;

  for (int k0 = 0; k0 < K; k0 += 32) {
    __syncthreads();                       // previous iter's ds_reads done
    gl2lds16(Amat + aOff0 + k0, lA0);
    gl2lds16(Amat + aOff1 + k0, lA1);
    gl2lds16(Bmat + bOff0 + k0, lB0);
    gl2lds16(Bmat + bOff1 + k0, lB1);
    __syncthreads();                       // drains vmcnt before ds_read

    short8 af[4], bf[4];
#pragma unroll
    for (int t = 0; t < 4; ++t) {
      af[t] = Asv[(wm * 64 + t * 16 + m16) * 4 + quad];  // A[m=lane&15][k=quad*8+j]
      bf[t] = Bsv[(wn * 64 + t * 16 + m16) * 4 + quad];  // B[n=lane&15][k=quad*8+j]
    }
#pragma unroll
    for (int mt = 0; mt < 4; ++mt)
#pragma unroll
      for (int nt = 0; nt < 4; ++nt)
        acc[mt][nt] = __builtin_amdgcn_mfma_f32_16x16x32_bf16(af[mt], bf[nt], acc[mt][nt], 0, 0, 0);
  }

  // C/D layout: col = lane&15, row = quad*4 + reg  [verified m89/m91]
#pragma unroll
  for (int mt = 0; mt < 4; ++mt) {
    const int row0 = blockM + wm * 64 + mt * 16 + quad * 4;
#pragma unroll
    for (int nt = 0; nt < 4; ++nt) {
      const int col = blockN + wn * 64 + nt * 16 + m16;
      f32x4 v = acc[mt][nt];
      if (FOLD) {
#pragma unroll
        for (int r = 0; r < 4; ++r) {
          size_t o = (size_t)(row0 + r) * N + col;
          outB[o] = f2bf(extra[o] + v[r]);
        }
      } else {
        const float bv = extra[col];
#pragma unroll
        for (int r = 0; r < 4; ++r) {
          size_t o = (size_t)(row0 + r) * N + col;
          outF[o] = v[r] + bv;
        }
      }
    }
  }
}

extern "C" void kernel_launch(void* const* d_in, const int* in_sizes, int n_in,
                              void* d_out, int out_size, void* d_ws, size_t ws_size,
                              hipStream_t stream) {
  const float* x    = (const float*)d_in[0];  // (8192, 4096)
  const float* W    = (const float*)d_in[1];  // (4096, 4096)
  const float* bias = (const float*)d_in[2];  // (4096,)
  const float* A    = (const float*)d_in[3];  // (256, 4096)
  const float* B    = (const float*)d_in[4];  // (4096, 256)
  const float* dv   = (const float*)d_in[5];  // (256,)
  const float* bv   = (const float*)d_in[6];  // (4096,)
  float* out = (float*)d_out;                 // (8192, 4096)

  char* ws = (char*)d_ws;
  unsigned short* xb  = (unsigned short*)ws;                       // 64MB  x bf16
  unsigned short* Wc  = (unsigned short*)(ws + (size_t)(64 << 20)); // 32MB  W+delta bf16
  unsigned short* Bd  = (unsigned short*)(ws + (size_t)(96 << 20)); // 2MB
  unsigned short* AbT = (unsigned short*)(ws + (size_t)(98 << 20)); // 2MB

  // 1. x -> bf16 (8192*4096/4 = 8388608 float4s)
  hipLaunchKernelGGL(k_cvt, dim3(32768), dim3(256), 0, stream, x, xb, 8388608);
  // 2. Bd, AbT
  hipLaunchKernelGGL(k_prep, dim3(4096), dim3(256), 0, stream, B, A, dv, bv, Bd, AbT);
  // 3. Wc = bf16(W + Bd @ AbT^T)   M=N=4096, K=256
  hipLaunchKernelGGL((gemm_bt<1>), dim3(32, 32), dim3(256), 0, stream,
                     Bd, AbT, 256, 4096, W, (float*)nullptr, Wc);
  // 4. out = xb @ Wc^T + bias      M=8192, N=4096, K=4096
  hipLaunchKernelGGL((gemm_bt<0>), dim3(32, 64), dim3(256), 0, stream,
                     xb, Wc, 4096, 4096, bias, out, (unsigned short*)nullptr);
}

// Round 2
// 640.112 us; speedup vs baseline: 1.0169x; 1.0169x over previous
//
#include <hip/hip_runtime.h>

// ---------------------------------------------------------------------------
// VeRA Linear: y = x @ (W + 4*diag(b) B diag(d) A)^T + bias
// T=8192, IN=OUT=4096, R=256, fp32 in/out.
// R2: XOR-swizzled LDS layout in gemm_bt (kills the 4 cyc/read bank
// conflicts from R1's transposed fragment mapping); merged+coalesced prep.
// ---------------------------------------------------------------------------

typedef __attribute__((ext_vector_type(8))) short short8;   // 8 bf16 = 4 VGPRs
typedef __attribute__((ext_vector_type(4))) float f32x4;    // MFMA acc

__device__ __forceinline__ unsigned short f2bf(float f) {
  union { float f; unsigned int u; } c; c.f = f;
  unsigned int u = c.u;
  unsigned int r = (u + 0x7fffu + ((u >> 16) & 1u)) >> 16;  // RNE, finite inputs
  return (unsigned short)r;
}

__device__ __forceinline__ void gl2lds16(const unsigned short* g, unsigned short* l) {
  __builtin_amdgcn_global_load_lds(
      (const __attribute__((address_space(1))) unsigned int*)g,
      (__attribute__((address_space(3))) unsigned int*)l, 16, 0, 0);
}

// Merged prep: blocks [0,32768) cvt x->bf16; [32768,36864) Bd; [36864,37888) A^T.
__global__ __launch_bounds__(256) void k_pre(const float* __restrict__ x,
                                             unsigned short* __restrict__ xb,
                                             const float* __restrict__ Bv,
                                             const float* __restrict__ Av,
                                             const float* __restrict__ dv,
                                             const float* __restrict__ bv,
                                             unsigned short* __restrict__ Bd,
                                             unsigned short* __restrict__ AbT) {
  __shared__ float tl[32][33];
  const int blk = blockIdx.x;
  const int tid = threadIdx.x;
  if (blk < 32768) {
    // x (8192x4096 fp32) -> bf16, 4 elems/thread
    int i = blk * 256 + tid;
    const float4 v = ((const float4*)x)[i];
    union { unsigned short u[4]; unsigned long long ll; } o;
    o.u[0] = f2bf(v.x); o.u[1] = f2bf(v.y); o.u[2] = f2bf(v.z); o.u[3] = f2bf(v.w);
    ((unsigned long long*)xb)[i] = o.ll;
  } else if (blk < 36864) {
    // Bd[o][r] = bf16(4 * b[o] * B[o][r] * d[r])
    int idx = (blk - 32768) * 256 + tid;
    int o = idx >> 8, r = idx & 255;
    Bd[idx] = f2bf(4.0f * bv[o] * Bv[idx] * dv[r]);
  } else {
    // AbT[i][r] = bf16(A[r][i]) via padded LDS tile (coalesced both sides)
    int blk2 = blk - 36864;           // 1024 blocks
    int ti = blk2 >> 3;               // i-block (32 wide), 0..127
    int tr = blk2 & 7;                // r-block (32 wide), 0..7
#pragma unroll
    for (int s = 0; s < 4; ++s) {
      int r = tr * 32 + s * 8 + (tid >> 5);
      int i = ti * 32 + (tid & 31);
      tl[s * 8 + (tid >> 5)][tid & 31] = Av[(size_t)r * 4096 + i];
    }
    __syncthreads();
#pragma unroll
    for (int s = 0; s < 4; ++s) {
      int iloc = s * 8 + (tid >> 5);
      int rloc = tid & 31;
      AbT[(size_t)(ti * 32 + iloc) * 256 + tr * 32 + rloc] = f2bf(tl[rloc][iloc]);
    }
  }
}

// C[m][n] = sum_k Amat[m][k]*Bmat[n][k]  (both row-major, K contiguous)
// FOLD=1: outB[m*N+n] = bf16(extra[m*N+n] + acc)   (extra = base W)
// FOLD=0: outF[m*N+n] = acc + extra[n]             (extra = bias)
// LDS layout swizzle: chunk (row16, kq) of a 16-row group stored at chunk
// index row16*4 + (kq ^ ((row16>>2)&3)). Staging dest stays base+lane*16
// (global_load_lds constraint); the GLOBAL k-offset is swizzled instead
// (within the same 64B row segment -> coalescing preserved).
template <int FOLD>
__global__ __launch_bounds__(256) void gemm_bt(const unsigned short* __restrict__ Amat,
                                               const unsigned short* __restrict__ Bmat,
                                               int K, int N,
                                               const float* __restrict__ extra,
                                               float* __restrict__ outF,
                                               unsigned short* __restrict__ outB) {
  __shared__ unsigned short As[128 * 32];   // 8KB, unpadded
  __shared__ unsigned short Bs[128 * 32];   // 8KB

  const int tid  = threadIdx.x;
  const int lane = tid & 63;
  const int wave = tid >> 6;     // 4 waves
  const int wm   = wave >> 1;    // 2x2 wave grid of 64x64 quadrants
  const int wn   = wave & 1;
  const int quad = lane >> 4;    // 0..3
  const int m16  = lane & 15;

  const int blockN = blockIdx.x * 128;
  const int blockM = blockIdx.y * 128;

  // staging: each wave fills 2 x 16-row segments of each 128x32 tile
  const int ldRow  = lane >> 2;                               // 0..15
  const int dstCol = (lane & 3) * 8;                          // LDS chunk = lane
  const int srcCol = ((lane & 3) ^ ((lane >> 4) & 3)) * 8;    // swizzled global k
  const int seg0   = wave * 2;

  const size_t aOff0 = (size_t)(blockM + seg0 * 16 + ldRow) * K + srcCol;
  const size_t aOff1 = (size_t)(blockM + seg0 * 16 + 16 + ldRow) * K + srcCol;
  const size_t bOff0 = (size_t)(blockN + seg0 * 16 + ldRow) * K + srcCol;
  const size_t bOff1 = (size_t)(blockN + seg0 * 16 + 16 + ldRow) * K + srcCol;

  unsigned short* lA0 = &As[(seg0 * 16 + ldRow) * 32 + dstCol];
  unsigned short* lA1 = &As[(seg0 * 16 + 16 + ldRow) * 32 + dstCol];
  unsigned short* lB0 = &Bs[(seg0 * 16 + ldRow) * 32 + dstCol];
  unsigned short* lB1 = &Bs[(seg0 * 16 + 16 + ldRow) * 32 + dstCol];

  f32x4 acc[4][4];
#pragma unroll
  for (int i = 0; i < 4; ++i)
#pragma unroll
    for (int j = 0; j < 4; ++j) acc[i][j] = (f32x4){0.f, 0.f, 0.f, 0.f};

  const short8* Asv = (const short8*)As;
  const short8* Bsv = (const short8*)Bs;
  const int qsw = quad ^ ((m16 >> 2) & 3);   // de-swizzled chunk column

  for (int k0 = 0; k0 < K; k0 += 32) {
    __syncthreads();                       // previous iter's ds_reads done
    gl2lds16(Amat + aOff0 + k0, lA0);
    gl2lds16(Amat + aOff1 + k0, lA1);
    gl2lds16(Bmat + bOff0 + k0, lB0);
    gl2lds16(Bmat + bOff1 + k0, lB1);
    __syncthreads();                       // drains vmcnt before ds_read

    short8 af[4], bf[4];
#pragma unroll
    for (int t = 0; t < 4; ++t) {
      af[t] = Asv[(wm * 64 + t * 16 + m16) * 4 + qsw];  // A[m=m16][k=quad*8+j]
      bf[t] = Bsv[(wn * 64 + t * 16 + m16) * 4 + qsw];  // B[n=m16][k=quad*8+j]
    }
#pragma unroll
    for (int mt = 0; mt < 4; ++mt)
#pragma unroll
      for (int nt = 0; nt < 4; ++nt)
        acc[mt][nt] = __builtin_amdgcn_mfma_f32_16x16x32_bf16(af[mt], bf[nt], acc[mt][nt], 0, 0, 0);
  }

  // C/D layout: col = lane&15, row = quad*4 + reg  [verified m89/m91]
#pragma unroll
  for (int mt = 0; mt < 4; ++mt) {
    const int row0 = blockM + wm * 64 + mt * 16 + quad * 4;
#pragma unroll
    for (int nt = 0; nt < 4; ++nt) {
      const int col = blockN + wn * 64 + nt * 16 + m16;
      f32x4 v = acc[mt][nt];
      if (FOLD) {
#pragma unroll
        for (int r = 0; r < 4; ++r) {
          size_t o = (size_t)(row0 + r) * N + col;
          outB[o] = f2bf(extra[o] + v[r]);
        }
      } else {
        const float bv = extra[col];
#pragma unroll
        for (int r = 0; r < 4; ++r) {
          size_t o = (size_t)(row0 + r) * N + col;
          outF[o] = v[r] + bv;
        }
      }
    }
  }
}

extern "C" void kernel_launch(void* const* d_in, const int* in_sizes, int n_in,
                              void* d_out, int out_size, void* d_ws, size_t ws_size,
                              hipStream_t stream) {
  const float* x    = (const float*)d_in[0];  // (8192, 4096)
  const float* W    = (const float*)d_in[1];  // (4096, 4096)
  const float* bias = (const float*)d_in[2];  // (4096,)
  const float* A    = (const float*)d_in[3];  // (256, 4096)
  const float* B    = (const float*)d_in[4];  // (4096, 256)
  const float* dv   = (const float*)d_in[5];  // (256,)
  const float* bv   = (const float*)d_in[6];  // (4096,)
  float* out = (float*)d_out;                 // (8192, 4096)

  char* ws = (char*)d_ws;
  unsigned short* xb  = (unsigned short*)ws;                        // 64MB x bf16
  unsigned short* Wc  = (unsigned short*)(ws + (size_t)(64 << 20)); // 32MB W+delta bf16
  unsigned short* Bd  = (unsigned short*)(ws + (size_t)(96 << 20)); // 2MB
  unsigned short* AbT = (unsigned short*)(ws + (size_t)(98 << 20)); // 2MB

  // 1. cvt + Bd + A^T in one launch
  hipLaunchKernelGGL(k_pre, dim3(37888), dim3(256), 0, stream,
                     x, xb, B, A, dv, bv, Bd, AbT);
  // 2. Wc = bf16(W + Bd @ AbT^T)   M=N=4096, K=256
  hipLaunchKernelGGL((gemm_bt<1>), dim3(32, 32), dim3(256), 0, stream,
                     Bd, AbT, 256, 4096, W, (float*)nullptr, Wc);
  // 3. out = xb @ Wc^T + bias      M=8192, N=4096, K=4096
  hipLaunchKernelGGL((gemm_bt<0>), dim3(32, 64), dim3(256), 0, stream,
                     xb, Wc, 4096, 4096, bias, out, (unsigned short*)nullptr);
}

// Round 3
// 587.819 us; speedup vs baseline: 1.1074x; 1.0890x over previous
//
#include <hip/hip_runtime.h>

// ---------------------------------------------------------------------------
// VeRA Linear: y = x @ (W + 4*diag(b) B diag(d) A)^T + bias
// T=8192, IN=OUT=4096, R=256, fp32 in/out.
// R3: BK=64 K-loop (halves barrier-drain count; 32 MFMA per barrier pair),
// XOR-swizzled 128x64 LDS tiles (chunk q stored at q^(row&7): 2 lanes/bank
// group per phase = free). R2 lesson: ~4 cyc/ds_read_b128 "conflict" is
// intrinsic to wide reads (m98 shows same ratio), not a real conflict.
// ---------------------------------------------------------------------------

typedef __attribute__((ext_vector_type(8))) short short8;   // 8 bf16 = 4 VGPRs
typedef __attribute__((ext_vector_type(4))) float f32x4;    // MFMA acc

__device__ __forceinline__ unsigned short f2bf(float f) {
  union { float f; unsigned int u; } c; c.f = f;
  unsigned int u = c.u;
  unsigned int r = (u + 0x7fffu + ((u >> 16) & 1u)) >> 16;  // RNE, finite inputs
  return (unsigned short)r;
}

__device__ __forceinline__ void gl2lds16(const unsigned short* g, unsigned short* l) {
  __builtin_amdgcn_global_load_lds(
      (const __attribute__((address_space(1))) unsigned int*)g,
      (__attribute__((address_space(3))) unsigned int*)l, 16, 0, 0);
}

// Merged prep: blocks [0,8192) cvt x->bf16 (4 float4/thread);
// [8192,12288) Bd; [12288,13312) A^T.
__global__ __launch_bounds__(256) void k_pre(const float* __restrict__ x,
                                             unsigned short* __restrict__ xb,
                                             const float* __restrict__ Bv,
                                             const float* __restrict__ Av,
                                             const float* __restrict__ dv,
                                             const float* __restrict__ bv,
                                             unsigned short* __restrict__ Bd,
                                             unsigned short* __restrict__ AbT) {
  __shared__ float tl[32][33];
  const int blk = blockIdx.x;
  const int tid = threadIdx.x;
  if (blk < 8192) {
#pragma unroll
    for (int s = 0; s < 4; ++s) {
      int i = blk * 1024 + s * 256 + tid;
      const float4 v = ((const float4*)x)[i];
      union { unsigned short u[4]; unsigned long long ll; } o;
      o.u[0] = f2bf(v.x); o.u[1] = f2bf(v.y); o.u[2] = f2bf(v.z); o.u[3] = f2bf(v.w);
      ((unsigned long long*)xb)[i] = o.ll;
    }
  } else if (blk < 12288) {
    // Bd[o][r] = bf16(4 * b[o] * B[o][r] * d[r])
    int idx = (blk - 8192) * 256 + tid;
    int o = idx >> 8, r = idx & 255;
    Bd[idx] = f2bf(4.0f * bv[o] * Bv[idx] * dv[r]);
  } else {
    // AbT[i][r] = bf16(A[r][i]) via padded LDS tile (coalesced both sides)
    int blk2 = blk - 12288;           // 1024 blocks
    int ti = blk2 >> 3;               // i-block, 0..127
    int tr = blk2 & 7;                // r-block, 0..7
#pragma unroll
    for (int s = 0; s < 4; ++s) {
      int r = tr * 32 + s * 8 + (tid >> 5);
      int i = ti * 32 + (tid & 31);
      tl[s * 8 + (tid >> 5)][tid & 31] = Av[(size_t)r * 4096 + i];
    }
    __syncthreads();
#pragma unroll
    for (int s = 0; s < 4; ++s) {
      int iloc = s * 8 + (tid >> 5);
      int rloc = tid & 31;
      AbT[(size_t)(ti * 32 + iloc) * 256 + tr * 32 + rloc] = f2bf(tl[rloc][iloc]);
    }
  }
}

// C[m][n] = sum_k Amat[m][k]*Bmat[n][k]  (both row-major, K contiguous, K%64==0)
// FOLD=1: outB[m*N+n] = bf16(extra[m*N+n] + acc)   (extra = base W)
// FOLD=0: outF[m*N+n] = acc + extra[n]             (extra = bias)
// LDS: 128x64 bf16 per tile (16KB), row = 8 chunks of 16B; chunk (row,q)
// stored at slot q^(row&7). Staging dest = base+lane*16 (HW constraint);
// the swizzle is applied to the GLOBAL k-offset (same 128B segment ->
// coalescing preserved). Fragment read de-swizzles with (h*4+quad)^(m16&7).
template <int FOLD>
__global__ __launch_bounds__(256) void gemm_bt(const unsigned short* __restrict__ Amat,
                                               const unsigned short* __restrict__ Bmat,
                                               int K, int N,
                                               const float* __restrict__ extra,
                                               float* __restrict__ outF,
                                               unsigned short* __restrict__ outB) {
  __shared__ unsigned short As[128 * 64];   // 16KB
  __shared__ unsigned short Bs[128 * 64];   // 16KB

  const int tid  = threadIdx.x;
  const int lane = tid & 63;
  const int wave = tid >> 6;     // 4 waves
  const int wm   = wave >> 1;    // 2x2 wave grid of 64x64 quadrants
  const int wn   = wave & 1;
  const int quad = lane >> 4;    // 0..3
  const int m16  = lane & 15;
  const int s7   = m16 & 7;

  const int blockN = blockIdx.x * 128;
  const int blockM = blockIdx.y * 128;

  // staging: instr n stages rows [n*32, n*32+32); thread covers row
  // r = (tid>>3)+n*32, dest chunk c = tid&7, source chunk q = c^(r&7)
  const int c    = tid & 7;
  const int rsub = tid >> 3;     // 0..31

  size_t aOff[4], bOff[4];
  unsigned short *dA[4], *dB[4];
#pragma unroll
  for (int n = 0; n < 4; ++n) {
    const int r = n * 32 + rsub;
    const int src = (c ^ (r & 7)) * 8;
    aOff[n] = (size_t)(blockM + r) * K + src;
    bOff[n] = (size_t)(blockN + r) * K + src;
    dA[n] = &As[(size_t)n * 2048 + tid * 8];
    dB[n] = &Bs[(size_t)n * 2048 + tid * 8];
  }

  f32x4 acc[4][4];
#pragma unroll
  for (int i = 0; i < 4; ++i)
#pragma unroll
    for (int j = 0; j < 4; ++j) acc[i][j] = (f32x4){0.f, 0.f, 0.f, 0.f};

  const short8* Asv = (const short8*)As;
  const short8* Bsv = (const short8*)Bs;

  for (int k0 = 0; k0 < K; k0 += 64) {
    __syncthreads();                       // previous iter's ds_reads done
#pragma unroll
    for (int n = 0; n < 4; ++n) {
      gl2lds16(Amat + aOff[n] + k0, dA[n]);
      gl2lds16(Bmat + bOff[n] + k0, dB[n]);
    }
    __syncthreads();                       // drains vmcnt before ds_read

#pragma unroll
    for (int h = 0; h < 2; ++h) {
      const int qs = (h * 4 + quad) ^ s7;
      short8 af[4], bf[4];
#pragma unroll
      for (int t = 0; t < 4; ++t) {
        af[t] = Asv[(wm * 64 + t * 16 + m16) * 8 + qs];  // A[m=m16][k=h*32+quad*8+j]
        bf[t] = Bsv[(wn * 64 + t * 16 + m16) * 8 + qs];
      }
#pragma unroll
      for (int mt = 0; mt < 4; ++mt)
#pragma unroll
        for (int nt = 0; nt < 4; ++nt)
          acc[mt][nt] = __builtin_amdgcn_mfma_f32_16x16x32_bf16(af[mt], bf[nt], acc[mt][nt], 0, 0, 0);
    }
  }

  // C/D layout: col = lane&15, row = quad*4 + reg  [verified m89/m91]
#pragma unroll
  for (int mt = 0; mt < 4; ++mt) {
    const int row0 = blockM + wm * 64 + mt * 16 + quad * 4;
#pragma unroll
    for (int nt = 0; nt < 4; ++nt) {
      const int col = blockN + wn * 64 + nt * 16 + m16;
      f32x4 v = acc[mt][nt];
      if (FOLD) {
#pragma unroll
        for (int r = 0; r < 4; ++r) {
          size_t o = (size_t)(row0 + r) * N + col;
          outB[o] = f2bf(extra[o] + v[r]);
        }
      } else {
        const float bv = extra[col];
#pragma unroll
        for (int r = 0; r < 4; ++r) {
          size_t o = (size_t)(row0 + r) * N + col;
          outF[o] = v[r] + bv;
        }
      }
    }
  }
}

extern "C" void kernel_launch(void* const* d_in, const int* in_sizes, int n_in,
                              void* d_out, int out_size, void* d_ws, size_t ws_size,
                              hipStream_t stream) {
  const float* x    = (const float*)d_in[0];  // (8192, 4096)
  const float* W    = (const float*)d_in[1];  // (4096, 4096)
  const float* bias = (const float*)d_in[2];  // (4096,)
  const float* A    = (const float*)d_in[3];  // (256, 4096)
  const float* B    = (const float*)d_in[4];  // (4096, 256)
  const float* dv   = (const float*)d_in[5];  // (256,)
  const float* bv   = (const float*)d_in[6];  // (4096,)
  float* out = (float*)d_out;                 // (8192, 4096)

  char* ws = (char*)d_ws;
  unsigned short* xb  = (unsigned short*)ws;                        // 64MB x bf16
  unsigned short* Wc  = (unsigned short*)(ws + (size_t)(64 << 20)); // 32MB W+delta bf16
  unsigned short* Bd  = (unsigned short*)(ws + (size_t)(96 << 20)); // 2MB
  unsigned short* AbT = (unsigned short*)(ws + (size_t)(98 << 20)); // 2MB

  // 1. cvt + Bd + A^T in one launch
  hipLaunchKernelGGL(k_pre, dim3(13312), dim3(256), 0, stream,
                     x, xb, B, A, dv, bv, Bd, AbT);
  // 2. Wc = bf16(W + Bd @ AbT^T)   M=N=4096, K=256
  hipLaunchKernelGGL((gemm_bt<1>), dim3(32, 32), dim3(256), 0, stream,
                     Bd, AbT, 256, 4096, W, (float*)nullptr, Wc);
  // 3. out = xb @ Wc^T + bias      M=8192, N=4096, K=4096
  hipLaunchKernelGGL((gemm_bt<0>), dim3(32, 64), dim3(256), 0, stream,
                     xb, Wc, 4096, 4096, bias, out, (unsigned short*)nullptr);
}